// Round 14
// baseline (45.516 us; speedup 1.0000x reference)
//
#include <hip/hip_runtime.h>

// out[8,8192] = x[8,8192] @ W^T, W = dequant4(qweight, scale, zero), GROUP=128.
// qweight: one byte value (0..255) per int32, [8192 n][4096 k-bytes], 2 nibbles
// per byte, low nibble = even k.
//
// R14: staging-granularity experiment (the single variable vs R12).
//  - Wave owns ONE 16-row tile x 512-k slice (KS=16). Staging = 16 ops,
//    each op reads ONE row's whole slice: 1 KB FULLY CONTIGUOUS
//    (64 lanes x 16B consecutive). R12 used 256B runs -> 3.7 TB/s; granule
//    ladder (64B->3.2, 256B->3.7) says coarser bursts recover stream BW.
//  - Single-buffered per wave (16 KB); stage stalls hidden by the OTHER
//    resident block (80 KB LDS -> 2 blocks/CU). No in-loop vmem at all.
//  - Swizzle inside each row's 64-int4 span: LDS[r][p] = G[r][p ^ (r&15)]
//    via per-lane source address (rule #21); ds_read applies the same XOR
//    -> 2-way banks, free. NT reverted (R13: NT hurt).
//  - A-slice (16 KB bf16 frags, rows 8..15 zero) built in LDS per block.
//  - C layout (HW-verified): col=lane&15, row=(lane>>4)*4+reg; rows 0..7 real.

typedef __attribute__((ext_vector_type(8))) short bf16x8;
typedef __attribute__((ext_vector_type(4))) float f32x4;

constexpr int Mdim  = 8;
constexpr int N     = 8192;
constexpr int K     = 8192;
constexpr int NG    = 64;           // groups per row
constexpr int KS    = 16;           // K splits
constexpr int KSL   = K / KS;       // 512 k per slice
constexpr int GPS   = KSL / 128;    // 4 groups per slice
constexpr int ROWI4 = K / 8;        // 1024 int4 per weight row
constexpr int SLI4  = KSL / 8;      // 64 int4 per row-slice (1 KB)
constexpr int SLKK  = KSL / 32;     // 16 A k-blocks per slice

__device__ __forceinline__ float nib_lo(int q) {
    return __int_as_float((q & 15) | 0x4B000000) - 8388608.0f;      // exact
}
__device__ __forceinline__ float nib_hi(int q) {
    return __int_as_float(((q >> 4) & 15) | 0x4B000000) - 8388608.0f;
}
__device__ __forceinline__ int pkbf(float lo, float hi) {           // 2xf32 -> 2xbf16 (RNE)
    int r;
    asm("v_cvt_pk_bf16_f32 %0, %1, %2" : "=v"(r) : "v"(lo), "v"(hi));
    return r;
}

__global__ __launch_bounds__(256, 2) void qmfma_kernel(
    const float* __restrict__ x,      // [8, 8192]
    const int*   __restrict__ qw,     // [8192, 4096]
    const float* __restrict__ scale,  // [8192, 64]
    const float* __restrict__ zero,   // [8192, 64]
    float*       __restrict__ out)    // [8, 8192] pre-zeroed
{
    __shared__ int4 As[SLKK * 64];    // 16KB: A fragments for this k-slice
    __shared__ int4 Bs[4][16 * SLI4]; // 4 x 16KB: per-wave B tile (16 rows x 1KB)

    const int tid  = threadIdx.x;
    const int lane = tid & 63;
    const int wave = tid >> 6;
    const int bid  = blockIdx.x;                  // 2048 blocks
    const int ks   = bid >> 7;                    // 0..15
    const int nb   = bid & 127;                   // n-block (64 cols)
    const int c0w  = nb * 64 + wave * 16;         // wave's 16 rows
    const int l15  = lane & 15;
    const int kb   = lane >> 4;                   // k-quad 0..3
    const int nl   = c0w + l15;                   // this lane's B row / C col

    const int g0 = ks * GPS;                      // first group of slice
    const int kq = ks * SLI4;                     // int4 offset of slice in a row

    const int4* __restrict__ qw4 = reinterpret_cast<const int4*>(qw);
    int4* BsW = Bs[wave];

    // ---- stage the tile: 16 ops, each 1 KB contiguous (one row's slice).
    // Per-lane source = slot (lane ^ (rr&15)) of the row's 64-int4 span;
    // LDS dest linear -> LDS[rr][p] = G[rr][p ^ rr].
    #pragma unroll
    for (int rr = 0; rr < 16; ++rr) {
        const int4* gp = qw4 + (size_t)(c0w + rr) * ROWI4 + kq + (lane ^ rr);
        __builtin_amdgcn_global_load_lds(
            (const __attribute__((address_space(1))) void*)gp,
            (__attribute__((address_space(3))) void*)(BsW + rr * SLI4),
            16, 0, 0);
    }

    // ---- scale/zero for all 4 groups of this lane's row: one float4 each
    const float4 sv = *reinterpret_cast<const float4*>(&scale[nl * NG + g0]);
    const float4 zv = *reinterpret_cast<const float4*>(&zero [nl * NG + g0]);
    const float sA[4] = {sv.x, sv.y, sv.z, sv.w};
    const float zA[4] = {zv.x, zv.y, zv.z, zv.w};

    // ---- build A-slice in LDS: 1024 fragments, 4 per thread (rows 8..15 zero)
    #pragma unroll
    for (int jf = tid; jf < SLKK * 64; jf += 256) {
        const int ll  = jf & 63;
        const int kk  = jf >> 6;
        const int row = ll & 15;
        const int k0  = ks * KSL + kk * 32 + (ll >> 4) * 8;
        float4 xa = {0.f, 0.f, 0.f, 0.f}, xb = {0.f, 0.f, 0.f, 0.f};
        if (row < Mdim) {
            const float4* xr = reinterpret_cast<const float4*>(x) + (size_t)row * (K / 4);
            xa = xr[k0 / 4];
            xb = xr[k0 / 4 + 1];
        }
        int4 rr;
        rr.x = pkbf(xa.x, xa.y);
        rr.y = pkbf(xa.z, xa.w);
        rr.z = pkbf(xb.x, xb.y);
        rr.w = pkbf(xb.z, xb.w);
        As[jf] = rr;
    }

    asm volatile("s_waitcnt vmcnt(0)" ::: "memory");   // B DMA + A x-loads done
    __syncthreads();                                   // As visible to all waves

    f32x4 acc = {0.f, 0.f, 0.f, 0.f};

    #pragma unroll
    for (int g = 0; g < GPS; ++g) {
        const float cs = sA[g], csz = zA[g] * sA[g];

        #pragma unroll
        for (int t = 0; t < 4; ++t) {
            const int s = g * 16 + t * 4 + kb;           // logical slot 0..63
            const int4 qa = BsW[l15 * SLI4 + (s ^ l15)]; // swizzled read

            union { int4 u; bf16x8 v; } A, B0;
            A.u = As[(g * 4 + t) * 64 + lane];

            B0.u.x = pkbf(fmaf(nib_lo(qa.x), cs, -csz), fmaf(nib_hi(qa.x), cs, -csz));
            B0.u.y = pkbf(fmaf(nib_lo(qa.y), cs, -csz), fmaf(nib_hi(qa.y), cs, -csz));
            B0.u.z = pkbf(fmaf(nib_lo(qa.z), cs, -csz), fmaf(nib_hi(qa.z), cs, -csz));
            B0.u.w = pkbf(fmaf(nib_lo(qa.w), cs, -csz), fmaf(nib_hi(qa.w), cs, -csz));

            acc = __builtin_amdgcn_mfma_f32_16x16x32_bf16(A.v, B0.v, acc, 0, 0, 0);
        }
    }

    // C: col = lane&15, row = kb*4 + i; rows 0..7 real -> kb < 2 stores.
    if (kb < 2) {
        #pragma unroll
        for (int i = 0; i < 4; ++i) {
            const int m = kb * 4 + i;
            atomicAdd(&out[(size_t)m * N + nl], acc[i]);
        }
    }
}

extern "C" void kernel_launch(void* const* d_in, const int* in_sizes, int n_in,
                              void* d_out, int out_size, void* d_ws, size_t ws_size,
                              hipStream_t stream) {
    const float* x     = (const float*)d_in[0];
    const int*   qw    = (const int*)d_in[1];
    const float* scale = (const float*)d_in[2];
    const float* zero  = (const float*)d_in[3];
    float*       out   = (float*)d_out;

    hipMemsetAsync(out, 0, (size_t)Mdim * N * sizeof(float), stream);
    qmfma_kernel<<<(N / 64) * KS, 256, 0, stream>>>(x, qw, scale, zero, out);
}

// Round 15
// 38.769 us; speedup vs baseline: 1.1740x; 1.1740x over previous
//
#include <hip/hip_runtime.h>

// out[8,8192] = x[8,8192] @ W^T, W = dequant4(qweight, scale, zero), GROUP=128.
// qweight: one byte value (0..255) per int32, [8192 n][4096 k-bytes], 2 nibbles
// per byte, low nibble = even k.
//
// R15: dual-path streaming experiment (single variable vs R12, the 36.6 µs
// best). Unified model from R12/R13/R14+m97: per-CU stream BW = ~4KB miss
// window / latency (L2 200cy->21 B/cy, L3 650->6.2, HBM 900->4.5). If the
// window lives BELOW the TCP (TCC/DRAM queues), an L3-hit stream (aux=0) and
// an NT/HBM stream (aux=2) have SEPARATE windows and their BW adds
// (~10.7 B/cy -> ~24 µs). If it's the TCP itself, they share and this is
// slightly worse than R12 -> R12 was the roofline. Staging ops alternate
// aux 0/2; NT half (67MB) re-streams from HBM each replay, normal half
// stays L3-resident. All else identical to R12:
//  - Per wave: 32 rows x 512-k slice (KS=16); 8 global_load_lds_dwordx4
//    per group (4 rows x 256B runs each), double-buffered, counted vmcnt(8).
//  - Linear LDS dest + source-side swizzle (slot ^= row&15) + same XOR on
//    ds_read (rule #21).
//  - A-slice (16KB bf16 frags, rows 8..15 zero) built in LDS per block.
//  - C layout (HW-verified): col=lane&15, row=(lane>>4)*4+reg; rows 0..7 real.

typedef __attribute__((ext_vector_type(8))) short bf16x8;
typedef __attribute__((ext_vector_type(4))) float f32x4;

constexpr int Mdim  = 8;
constexpr int N     = 8192;
constexpr int K     = 8192;
constexpr int NG    = 64;           // groups per row
constexpr int KS    = 16;           // K splits
constexpr int KSL   = K / KS;       // 512 k per slice
constexpr int GPS   = KSL / 128;    // 4 groups per slice
constexpr int ROWI4 = K / 8;        // 1024 int4 per weight row
constexpr int SLKK  = KSL / 32;     // 16 A k-blocks per slice

__device__ __forceinline__ float nib_lo(int q) {
    return __int_as_float((q & 15) | 0x4B000000) - 8388608.0f;      // exact
}
__device__ __forceinline__ float nib_hi(int q) {
    return __int_as_float(((q >> 4) & 15) | 0x4B000000) - 8388608.0f;
}
__device__ __forceinline__ int pkbf(float lo, float hi) {           // 2xf32 -> 2xbf16 (RNE)
    int r;
    asm("v_cvt_pk_bf16_f32 %0, %1, %2" : "=v"(r) : "v"(lo), "v"(hi));
    return r;
}

// Stage one 128-k group (32 rows x 16 int4 slots) into wave-private LDS.
// Linear dest; source pre-swizzled so LDS(row, s) = G(row, s ^ (row&15)).
// Ops alternate cache policy: even i -> aux=0 (L3-resident path),
// odd i -> aux=2 (NT/HBM path). Literal aux per call (builtin requirement).
__device__ __forceinline__ void stage_group(const int4* __restrict__ qw4,
                                            int4* dst, int c0, int kq,
                                            int lane, int g) {
    #pragma unroll
    for (int i = 0; i < 8; ++i) {
        const int rl   = 4 * i + (lane >> 4);                 // local row 0..31
        const int gcol = kq + g * 16 + ((lane & 15) ^ (rl & 15));
        const int4* gp = qw4 + (size_t)(c0 + rl) * ROWI4 + gcol;
        if (i & 1)
            __builtin_amdgcn_global_load_lds(
                (const __attribute__((address_space(1))) void*)gp,
                (__attribute__((address_space(3))) void*)(dst + i * 64),
                16, 0, 2 /* NT: HBM stream */);
        else
            __builtin_amdgcn_global_load_lds(
                (const __attribute__((address_space(1))) void*)gp,
                (__attribute__((address_space(3))) void*)(dst + i * 64),
                16, 0, 0 /* normal: L3-resident stream */);
    }
}

__global__ __launch_bounds__(256, 2) void qmfma_kernel(
    const float* __restrict__ x,      // [8, 8192]
    const int*   __restrict__ qw,     // [8192, 4096]
    const float* __restrict__ scale,  // [8192, 64]
    const float* __restrict__ zero,   // [8192, 64]
    float*       __restrict__ out)    // [8, 8192] pre-zeroed
{
    __shared__ int4 As[SLKK * 64];    // 16KB: A fragments for this k-slice
    __shared__ int4 Bs[4][2][512];    // 64KB: per-wave double-buffered B stage

    const int tid  = threadIdx.x;
    const int lane = tid & 63;
    const int wave = tid >> 6;
    const int bid  = blockIdx.x;                  // 1024 blocks
    const int ks   = bid >> 6;                    // 0..15
    const int nb   = bid & 63;                    // n-block (128 cols)
    const int c0   = nb * 128 + wave * 32;        // wave's first col (32 rows)
    const int nl0  = c0 + (lane & 15);            // tile0 row / C col
    const int nl1  = nl0 + 16;                    // tile1
    const int kb   = lane >> 4;                   // k-quad 0..3
    const int r    = lane & 15;

    const int g0 = ks * GPS;                      // first group of slice
    const int kq = ks * (KSL / 8);                // int4 offset of slice in a row

    const int4* __restrict__ qw4 = reinterpret_cast<const int4*>(qw);
    int4 (*BsW)[512] = Bs[wave];

    // ---- issue group-0 staging FIRST (latency hides under the A build)
    stage_group(qw4, BsW[0], c0, kq, lane, 0);

    // ---- scale/zero for all 4 groups of the slice: one float4 per stream
    const float4 sv0 = *reinterpret_cast<const float4*>(&scale[nl0 * NG + g0]);
    const float4 zv0 = *reinterpret_cast<const float4*>(&zero [nl0 * NG + g0]);
    const float4 sv1 = *reinterpret_cast<const float4*>(&scale[nl1 * NG + g0]);
    const float4 zv1 = *reinterpret_cast<const float4*>(&zero [nl1 * NG + g0]);
    const float sA0[4] = {sv0.x, sv0.y, sv0.z, sv0.w};
    const float zA0[4] = {zv0.x, zv0.y, zv0.z, zv0.w};
    const float sA1[4] = {sv1.x, sv1.y, sv1.z, sv1.w};
    const float zA1[4] = {zv1.x, zv1.y, zv1.z, zv1.w};

    // ---- build A-slice in LDS: 1024 fragments, 4 per thread (rows 8..15 zero)
    #pragma unroll
    for (int jf = tid; jf < SLKK * 64; jf += 256) {
        const int ll  = jf & 63;
        const int kk  = jf >> 6;
        const int row = ll & 15;
        const int k0  = ks * KSL + kk * 32 + (ll >> 4) * 8;
        float4 xa = {0.f, 0.f, 0.f, 0.f}, xb = {0.f, 0.f, 0.f, 0.f};
        if (row < Mdim) {
            const float4* xr = reinterpret_cast<const float4*>(x) + (size_t)row * (K / 4);
            xa = xr[k0 / 4];
            xb = xr[k0 / 4 + 1];
        }
        int4 rr;
        rr.x = pkbf(xa.x, xa.y);
        rr.y = pkbf(xa.z, xa.w);
        rr.z = pkbf(xb.x, xb.y);
        rr.w = pkbf(xb.z, xb.w);
        As[jf] = rr;
    }

    asm volatile("s_waitcnt vmcnt(0)" ::: "memory");   // A x-loads + group-0 DMA done
    __syncthreads();                                   // As visible to all waves

    f32x4 acc0 = {0.f, 0.f, 0.f, 0.f};
    f32x4 acc1 = {0.f, 0.f, 0.f, 0.f};

    #pragma unroll
    for (int g = 0; g < GPS; ++g) {
        const int cur = g & 1;
        if (g + 1 < GPS) {
            // prior ds_reads of the buffer we're about to overwrite are done
            asm volatile("s_waitcnt lgkmcnt(0)" ::: "memory");
            __builtin_amdgcn_sched_barrier(0);
            stage_group(qw4, BsW[cur ^ 1], c0, kq, lane, g + 1);
            // current buffer ready: all but the 8 newest loads complete
            asm volatile("s_waitcnt vmcnt(8)" ::: "memory");
        } else {
            asm volatile("s_waitcnt vmcnt(0)" ::: "memory");
        }
        __builtin_amdgcn_sched_barrier(0);

        const float cs0 = sA0[g], csz0 = zA0[g] * sA0[g];
        const float cs1 = sA1[g], csz1 = zA1[g] * sA1[g];

        #pragma unroll
        for (int t = 0; t < 4; ++t) {
            const int j = t * 4 + kb;
            const int4 qa = BsW[cur][r * 16 + (j ^ r)];          // tile0 raw
            const int4 qb = BsW[cur][(16 + r) * 16 + (j ^ r)];   // tile1 raw

            union { int4 u; bf16x8 v; } A, B0, B1;
            A.u = As[(g * 4 + t) * 64 + lane];

            B0.u.x = pkbf(fmaf(nib_lo(qa.x), cs0, -csz0), fmaf(nib_hi(qa.x), cs0, -csz0));
            B0.u.y = pkbf(fmaf(nib_lo(qa.y), cs0, -csz0), fmaf(nib_hi(qa.y), cs0, -csz0));
            B0.u.z = pkbf(fmaf(nib_lo(qa.z), cs0, -csz0), fmaf(nib_hi(qa.z), cs0, -csz0));
            B0.u.w = pkbf(fmaf(nib_lo(qa.w), cs0, -csz0), fmaf(nib_hi(qa.w), cs0, -csz0));
            B1.u.x = pkbf(fmaf(nib_lo(qb.x), cs1, -csz1), fmaf(nib_hi(qb.x), cs1, -csz1));
            B1.u.y = pkbf(fmaf(nib_lo(qb.y), cs1, -csz1), fmaf(nib_hi(qb.y), cs1, -csz1));
            B1.u.z = pkbf(fmaf(nib_lo(qb.z), cs1, -csz1), fmaf(nib_hi(qb.z), cs1, -csz1));
            B1.u.w = pkbf(fmaf(nib_lo(qb.w), cs1, -csz1), fmaf(nib_hi(qb.w), cs1, -csz1));

            acc0 = __builtin_amdgcn_mfma_f32_16x16x32_bf16(A.v, B0.v, acc0, 0, 0, 0);
            acc1 = __builtin_amdgcn_mfma_f32_16x16x32_bf16(A.v, B1.v, acc1, 0, 0, 0);
        }
    }

    // C: col = lane&15, row = kb*4 + i; rows 0..7 real -> kb < 2 stores.
    if (kb < 2) {
        #pragma unroll
        for (int i = 0; i < 4; ++i) {
            const int m = kb * 4 + i;
            atomicAdd(&out[(size_t)m * N + nl0], acc0[i]);
            atomicAdd(&out[(size_t)m * N + nl1], acc1[i]);
        }
    }
}

extern "C" void kernel_launch(void* const* d_in, const int* in_sizes, int n_in,
                              void* d_out, int out_size, void* d_ws, size_t ws_size,
                              hipStream_t stream) {
    const float* x     = (const float*)d_in[0];
    const int*   qw    = (const int*)d_in[1];
    const float* scale = (const float*)d_in[2];
    const float* zero  = (const float*)d_in[3];
    float*       out   = (float*)d_out;

    hipMemsetAsync(out, 0, (size_t)Mdim * N * sizeof(float), stream);
    qmfma_kernel<<<(N / 128) * KS, 256, 0, stream>>>(x, qw, scale, zero, out);
}

// Round 16
// 36.002 us; speedup vs baseline: 1.2642x; 1.0769x over previous
//
#include <hip/hip_runtime.h>

// out[8,8192] = x[8,8192] @ W^T, W = dequant4(qweight, scale, zero), GROUP=128.
// qweight: one byte value (0..255) per int32, [8192 n][4096 k-bytes], 2 nibbles
// per byte, low nibble = even k.
//
// R16 = R12 restored (best: 36.6 µs). Roofline case closed by R13/R14/R15:
// one-touch weight stream caps at ~3.7 TB/s on this part regardless of
// occupancy (R9), path (reg vs DMA, R8/R12), granule >=256B (R14), cache
// policy (R13), or dual-policy streams (R15). 134 MB / 3.7 TB/s ~= 36 µs.
//  - Per wave: 32 weight rows x 512-k slice (KS=16); each group staged as 8
//    global_load_lds_dwordx4 (contiguous 256B runs, 4 rows per op).
//  - Linear LDS dest + source-side swizzle (slot ^= row&15) + same XOR on
//    ds_read (rule #21) -> ~2-way read-back, free.
//  - Double-buffered per wave; counted s_waitcnt vmcnt(8) keeps the next
//    group's 8 loads in flight across compute (no drain-to-0 in loop).
//  - A-slice (16 KB bf16 frags, rows 8..15 zero) built in LDS per block.
//  - C layout (HW-verified): col=lane&15, row=(lane>>4)*4+reg; rows 0..7 real.

typedef __attribute__((ext_vector_type(8))) short bf16x8;
typedef __attribute__((ext_vector_type(4))) float f32x4;

constexpr int Mdim  = 8;
constexpr int N     = 8192;
constexpr int K     = 8192;
constexpr int NG    = 64;           // groups per row
constexpr int KS    = 16;           // K splits
constexpr int KSL   = K / KS;       // 512 k per slice
constexpr int GPS   = KSL / 128;    // 4 groups per slice
constexpr int ROWI4 = K / 8;        // 1024 int4 per weight row
constexpr int SLKK  = KSL / 32;     // 16 A k-blocks per slice

__device__ __forceinline__ float nib_lo(int q) {
    return __int_as_float((q & 15) | 0x4B000000) - 8388608.0f;      // exact
}
__device__ __forceinline__ float nib_hi(int q) {
    return __int_as_float(((q >> 4) & 15) | 0x4B000000) - 8388608.0f;
}
__device__ __forceinline__ int pkbf(float lo, float hi) {           // 2xf32 -> 2xbf16 (RNE)
    int r;
    asm("v_cvt_pk_bf16_f32 %0, %1, %2" : "=v"(r) : "v"(lo), "v"(hi));
    return r;
}

// Stage one 128-k group (32 rows x 16 int4 slots) into wave-private LDS.
// Linear dest; source pre-swizzled so LDS(row, s) = G(row, s ^ (row&15)).
__device__ __forceinline__ void stage_group(const int4* __restrict__ qw4,
                                            int4* dst, int c0, int kq,
                                            int lane, int g) {
    #pragma unroll
    for (int i = 0; i < 8; ++i) {
        const int rl   = 4 * i + (lane >> 4);                 // local row 0..31
        const int gcol = kq + g * 16 + ((lane & 15) ^ (rl & 15));
        const int4* gp = qw4 + (size_t)(c0 + rl) * ROWI4 + gcol;
        __builtin_amdgcn_global_load_lds(
            (const __attribute__((address_space(1))) void*)gp,
            (__attribute__((address_space(3))) void*)(dst + i * 64),
            16, 0, 0);
    }
}

__global__ __launch_bounds__(256, 2) void qmfma_kernel(
    const float* __restrict__ x,      // [8, 8192]
    const int*   __restrict__ qw,     // [8192, 4096]
    const float* __restrict__ scale,  // [8192, 64]
    const float* __restrict__ zero,   // [8192, 64]
    float*       __restrict__ out)    // [8, 8192] pre-zeroed
{
    __shared__ int4 As[SLKK * 64];    // 16KB: A fragments for this k-slice
    __shared__ int4 Bs[4][2][512];    // 64KB: per-wave double-buffered B stage

    const int tid  = threadIdx.x;
    const int lane = tid & 63;
    const int wave = tid >> 6;
    const int bid  = blockIdx.x;                  // 1024 blocks
    const int ks   = bid >> 6;                    // 0..15
    const int nb   = bid & 63;                    // n-block (128 cols)
    const int c0   = nb * 128 + wave * 32;        // wave's first col (32 rows)
    const int nl0  = c0 + (lane & 15);            // tile0 row / C col
    const int nl1  = nl0 + 16;                    // tile1
    const int kb   = lane >> 4;                   // k-quad 0..3
    const int r    = lane & 15;

    const int g0 = ks * GPS;                      // first group of slice
    const int kq = ks * (KSL / 8);                // int4 offset of slice in a row

    const int4* __restrict__ qw4 = reinterpret_cast<const int4*>(qw);
    int4 (*BsW)[512] = Bs[wave];

    // ---- issue group-0 staging FIRST (latency hides under the A build)
    stage_group(qw4, BsW[0], c0, kq, lane, 0);

    // ---- scale/zero for all 4 groups of the slice: one float4 per stream
    const float4 sv0 = *reinterpret_cast<const float4*>(&scale[nl0 * NG + g0]);
    const float4 zv0 = *reinterpret_cast<const float4*>(&zero [nl0 * NG + g0]);
    const float4 sv1 = *reinterpret_cast<const float4*>(&scale[nl1 * NG + g0]);
    const float4 zv1 = *reinterpret_cast<const float4*>(&zero [nl1 * NG + g0]);
    const float sA0[4] = {sv0.x, sv0.y, sv0.z, sv0.w};
    const float zA0[4] = {zv0.x, zv0.y, zv0.z, zv0.w};
    const float sA1[4] = {sv1.x, sv1.y, sv1.z, sv1.w};
    const float zA1[4] = {zv1.x, zv1.y, zv1.z, zv1.w};

    // ---- build A-slice in LDS: 1024 fragments, 4 per thread (rows 8..15 zero)
    #pragma unroll
    for (int jf = tid; jf < SLKK * 64; jf += 256) {
        const int ll  = jf & 63;
        const int kk  = jf >> 6;
        const int row = ll & 15;
        const int k0  = ks * KSL + kk * 32 + (ll >> 4) * 8;
        float4 xa = {0.f, 0.f, 0.f, 0.f}, xb = {0.f, 0.f, 0.f, 0.f};
        if (row < Mdim) {
            const float4* xr = reinterpret_cast<const float4*>(x) + (size_t)row * (K / 4);
            xa = xr[k0 / 4];
            xb = xr[k0 / 4 + 1];
        }
        int4 rr;
        rr.x = pkbf(xa.x, xa.y);
        rr.y = pkbf(xa.z, xa.w);
        rr.z = pkbf(xb.x, xb.y);
        rr.w = pkbf(xb.z, xb.w);
        As[jf] = rr;
    }

    asm volatile("s_waitcnt vmcnt(0)" ::: "memory");   // A x-loads + group-0 DMA done
    __syncthreads();                                   // As visible to all waves

    f32x4 acc0 = {0.f, 0.f, 0.f, 0.f};
    f32x4 acc1 = {0.f, 0.f, 0.f, 0.f};

    #pragma unroll
    for (int g = 0; g < GPS; ++g) {
        const int cur = g & 1;
        if (g + 1 < GPS) {
            // prior ds_reads of the buffer we're about to overwrite are done
            asm volatile("s_waitcnt lgkmcnt(0)" ::: "memory");
            __builtin_amdgcn_sched_barrier(0);
            stage_group(qw4, BsW[cur ^ 1], c0, kq, lane, g + 1);
            // current buffer ready: all but the 8 newest loads complete
            asm volatile("s_waitcnt vmcnt(8)" ::: "memory");
        } else {
            asm volatile("s_waitcnt vmcnt(0)" ::: "memory");
        }
        __builtin_amdgcn_sched_barrier(0);

        const float cs0 = sA0[g], csz0 = zA0[g] * sA0[g];
        const float cs1 = sA1[g], csz1 = zA1[g] * sA1[g];

        #pragma unroll
        for (int t = 0; t < 4; ++t) {
            const int j = t * 4 + kb;
            const int4 qa = BsW[cur][r * 16 + (j ^ r)];          // tile0 raw
            const int4 qb = BsW[cur][(16 + r) * 16 + (j ^ r)];   // tile1 raw

            union { int4 u; bf16x8 v; } A, B0, B1;
            A.u = As[(g * 4 + t) * 64 + lane];

            B0.u.x = pkbf(fmaf(nib_lo(qa.x), cs0, -csz0), fmaf(nib_hi(qa.x), cs0, -csz0));
            B0.u.y = pkbf(fmaf(nib_lo(qa.y), cs0, -csz0), fmaf(nib_hi(qa.y), cs0, -csz0));
            B0.u.z = pkbf(fmaf(nib_lo(qa.z), cs0, -csz0), fmaf(nib_hi(qa.z), cs0, -csz0));
            B0.u.w = pkbf(fmaf(nib_lo(qa.w), cs0, -csz0), fmaf(nib_hi(qa.w), cs0, -csz0));
            B1.u.x = pkbf(fmaf(nib_lo(qb.x), cs1, -csz1), fmaf(nib_hi(qb.x), cs1, -csz1));
            B1.u.y = pkbf(fmaf(nib_lo(qb.y), cs1, -csz1), fmaf(nib_hi(qb.y), cs1, -csz1));
            B1.u.z = pkbf(fmaf(nib_lo(qb.z), cs1, -csz1), fmaf(nib_hi(qb.z), cs1, -csz1));
            B1.u.w = pkbf(fmaf(nib_lo(qb.w), cs1, -csz1), fmaf(nib_hi(qb.w), cs1, -csz1));

            acc0 = __builtin_amdgcn_mfma_f32_16x16x32_bf16(A.v, B0.v, acc0, 0, 0, 0);
            acc1 = __builtin_amdgcn_mfma_f32_16x16x32_bf16(A.v, B1.v, acc1, 0, 0, 0);
        }
    }

    // C: col = lane&15, row = kb*4 + i; rows 0..7 real -> kb < 2 stores.
    if (kb < 2) {
        #pragma unroll
        for (int i = 0; i < 4; ++i) {
            const int m = kb * 4 + i;
            atomicAdd(&out[(size_t)m * N + nl0], acc0[i]);
            atomicAdd(&out[(size_t)m * N + nl1], acc1[i]);
        }
    }
}

extern "C" void kernel_launch(void* const* d_in, const int* in_sizes, int n_in,
                              void* d_out, int out_size, void* d_ws, size_t ws_size,
                              hipStream_t stream) {
    const float* x     = (const float*)d_in[0];
    const int*   qw    = (const int*)d_in[1];
    const float* scale = (const float*)d_in[2];
    const float* zero  = (const float*)d_in[3];
    float*       out   = (float*)d_out;

    hipMemsetAsync(out, 0, (size_t)Mdim * N * sizeof(float), stream);
    qmfma_kernel<<<(N / 128) * KS, 256, 0, stream>>>(x, qw, scale, zero, out);
}